// Round 3
// baseline (341.809 us; speedup 1.0000x reference)
//
#include <hip/hip_runtime.h>
#include <cstdint>
#include <cstddef>

#define B_ 2
#define T_ 2048
#define C_ 768
#define H_ 12
#define D_ 64

typedef __attribute__((ext_vector_type(8))) short s16x8;
typedef __attribute__((ext_vector_type(4))) float fx4;

static __device__ __forceinline__ unsigned short f2bf(float f) {
  unsigned u = __builtin_bit_cast(unsigned, f);
  unsigned r = u + 0x7fffu + ((u >> 16) & 1u);
  return (unsigned short)(r >> 16);
}

static __device__ __forceinline__ void glds16(const unsigned short* g, unsigned short* l) {
  __builtin_amdgcn_global_load_lds(
      (const __attribute__((address_space(1))) void*)(g),
      (__attribute__((address_space(3))) void*)(l), 16, 0, 0);
}

// ---------------- weight transpose + cast: W[R][C] fp32 -> Wt[C][R] bf16 ----
__global__ __launch_bounds__(256) void transpose_cast(
    const float* __restrict__ W, unsigned short* __restrict__ Wt, int R, int C) {
  __shared__ float tile[32][33];
  int tx = threadIdx.x & 31;
  int ty = threadIdx.x >> 5;  // 0..7
  int c0 = blockIdx.x * 32, r0 = blockIdx.y * 32;
#pragma unroll
  for (int i = 0; i < 4; ++i)
    tile[ty + i * 8][tx] = W[(size_t)(r0 + ty + i * 8) * C + (c0 + tx)];
  __syncthreads();
#pragma unroll
  for (int i = 0; i < 4; ++i)
    Wt[(size_t)(c0 + ty + i * 8) * R + (r0 + tx)] = f2bf(tile[tx][ty + i * 8]);
}

// ---------------- out[m][n] = resid[m][n] + bias[n]  (float4) ---------------
__global__ __launch_bounds__(256) void add_bias_init(
    const float* __restrict__ resid, const float* __restrict__ bias,
    float* __restrict__ out, int Nq) {  // Nq = N/4
  int idx = blockIdx.x * 256 + threadIdx.x;
  float4 r = ((const float4*)resid)[idx];
  float4 b = ((const float4*)bias)[idx % Nq];
  out[idx * 4 + 0] = r.x + b.x;
  out[idx * 4 + 1] = r.y + b.y;
  out[idx * 4 + 2] = r.z + b.z;
  out[idx * 4 + 3] = r.w + b.w;
}

// ---------------- layernorm fp32 -> bf16 ------------------------------------
__global__ __launch_bounds__(256) void layernorm_bf16(
    const float* __restrict__ X, const float* __restrict__ g,
    const float* __restrict__ bb, unsigned short* __restrict__ O) {
  int row = blockIdx.x, tid = threadIdx.x;
  const float* xr = X + (size_t)row * C_;
  float v0 = xr[tid], v1 = xr[tid + 256], v2 = xr[tid + 512];
  float s = v0 + v1 + v2;
  float s2 = v0 * v0 + v1 * v1 + v2 * v2;
#pragma unroll
  for (int off = 1; off < 64; off <<= 1) {
    s += __shfl_xor(s, off);
    s2 += __shfl_xor(s2, off);
  }
  __shared__ float ps[8];
  int wv = tid >> 6;
  if ((tid & 63) == 0) { ps[wv] = s; ps[wv + 4] = s2; }
  __syncthreads();
  s = ps[0] + ps[1] + ps[2] + ps[3];
  s2 = ps[4] + ps[5] + ps[6] + ps[7];
  float mu = s * (1.f / C_);
  float var = s2 * (1.f / C_) - mu * mu;
  float rstd = rsqrtf(var + 1e-5f);
  unsigned short* orow = O + (size_t)row * C_;
  orow[tid]       = f2bf((v0 - mu) * rstd * g[tid]       + bb[tid]);
  orow[tid + 256] = f2bf((v1 - mu) * rstd * g[tid + 256] + bb[tid + 256]);
  orow[tid + 512] = f2bf((v2 - mu) * rstd * g[tid + 512] + bb[tid + 512]);
}

// ---------------- GEMM (m97-style): C[M,N] = A[M,K] * Bt[N,K]^T + bias ------
// MODE 0: scatter into Q [bh,t,d], K [bh,t,d], Vt [bh,d,t]  (QKV)
// MODE 2: outB = gelu(C + bias) (bf16)
template <int BM, int BN, int MODE>
__global__ __launch_bounds__(256) void gemm_lds(
    const unsigned short* __restrict__ A, const unsigned short* __restrict__ Bt,
    const float* __restrict__ bias,
    unsigned short* __restrict__ outB,
    unsigned short* __restrict__ qO, unsigned short* __restrict__ kO,
    unsigned short* __restrict__ vtO, int M, int N, int K) {
  constexpr int AT = BM / 32;
  constexpr int BT = BN / 32;
  constexpr int LA = (BM * 32 * 2) / (256 * 16);
  constexpr int LB = (BN * 32 * 2) / (256 * 16);
  __shared__ __align__(16) unsigned short As[BM * 32];
  __shared__ __align__(16) unsigned short Bs[BN * 32];
  int tid = threadIdx.x;
  int wv = tid >> 6, lane = tid & 63, quad = lane >> 4, l15 = lane & 15;
  int wm = wv >> 1, wn = wv & 1;
  int m0 = blockIdx.y * BM, n0 = blockIdx.x * BN;
  fx4 acc[AT][BT];
#pragma unroll
  for (int i = 0; i < AT; ++i)
#pragma unroll
    for (int j = 0; j < BT; ++j) acc[i][j] = fx4{0.f, 0.f, 0.f, 0.f};

  int nk = K >> 5;
  for (int kt = 0; kt < nk; ++kt) {
    __syncthreads();
#pragma unroll
    for (int i = 0; i < LA; ++i) {
      int e = (i * 256 + tid) * 8;
      int row = e >> 5, col = e & 31;
      glds16(&A[(size_t)(m0 + row) * K + kt * 32 + col],
             &As[(i * 256 + (tid & ~63)) * 8]);
    }
#pragma unroll
    for (int i = 0; i < LB; ++i) {
      int e = (i * 256 + tid) * 8;
      int row = e >> 5, col = e & 31;
      glds16(&Bt[(size_t)(n0 + row) * K + kt * 32 + col],
             &Bs[(i * 256 + (tid & ~63)) * 8]);
    }
    __syncthreads();
    s16x8 af[AT], bf[BT];
#pragma unroll
    for (int mt = 0; mt < AT; ++mt)
      af[mt] = *(const s16x8*)&As[(wm * (BM / 2) + mt * 16 + l15) * 32 + quad * 8];
#pragma unroll
    for (int nt = 0; nt < BT; ++nt)
      bf[nt] = *(const s16x8*)&Bs[(wn * (BN / 2) + nt * 16 + l15) * 32 + quad * 8];
#pragma unroll
    for (int mt = 0; mt < AT; ++mt)
#pragma unroll
      for (int nt = 0; nt < BT; ++nt)
        acc[mt][nt] = __builtin_amdgcn_mfma_f32_16x16x32_bf16(af[mt], bf[nt], acc[mt][nt], 0, 0, 0);
  }

#pragma unroll
  for (int mt = 0; mt < AT; ++mt)
#pragma unroll
    for (int nt = 0; nt < BT; ++nt)
#pragma unroll
      for (int r = 0; r < 4; ++r) {
        int m = m0 + wm * (BM / 2) + mt * 16 + quad * 4 + r;
        int n = n0 + wn * (BN / 2) + nt * 16 + l15;
        float v = acc[mt][nt][r] + bias[n];
        if (MODE == 0) {
          int which = n / C_;
          int within = n - which * C_;
          int hd = within >> 6, d = within & 63;
          int bbx = m >> 11, t = m & 2047;
          size_t bh = (size_t)(bbx * H_ + hd);
          unsigned short bv = f2bf(v);
          if (which == 0)      qO[(bh * T_ + t) * D_ + d] = bv;
          else if (which == 1) kO[(bh * T_ + t) * D_ + d] = bv;
          else                 vtO[(bh * D_ + d) * T_ + t] = bv;
        } else {
          float gl = 0.5f * v * (1.f + erff(v * 0.70710678118654752f));
          outB[(size_t)m * N + n] = f2bf(gl);
        }
      }
}

// ---------------- split-K GEMM: out[M,N] += A[M,k-chunk] * Bt[N,k-chunk]^T --
// blockIdx.z picks the K chunk (KC elements). Output pre-initialized with
// resid + bias by add_bias_init; partials combined via HW fp32 atomics.
template <int BM, int BN>
__global__ __launch_bounds__(256) void gemm_splitk(
    const unsigned short* __restrict__ A, const unsigned short* __restrict__ Bt,
    float* __restrict__ outF, int M, int N, int K, int KC) {
  constexpr int AT = BM / 32;
  constexpr int BT = BN / 32;
  constexpr int LA = (BM * 32 * 2) / (256 * 16);
  constexpr int LB = (BN * 32 * 2) / (256 * 16);
  __shared__ __align__(16) unsigned short As[BM * 32];
  __shared__ __align__(16) unsigned short Bs[BN * 32];
  int tid = threadIdx.x;
  int wv = tid >> 6, lane = tid & 63, quad = lane >> 4, l15 = lane & 15;
  int wm = wv >> 1, wn = wv & 1;
  int m0 = blockIdx.y * BM, n0 = blockIdx.x * BN;
  int kbase = blockIdx.z * KC;
  fx4 acc[AT][BT];
#pragma unroll
  for (int i = 0; i < AT; ++i)
#pragma unroll
    for (int j = 0; j < BT; ++j) acc[i][j] = fx4{0.f, 0.f, 0.f, 0.f};

  int nk = KC >> 5;
  for (int kt = 0; kt < nk; ++kt) {
    __syncthreads();
#pragma unroll
    for (int i = 0; i < LA; ++i) {
      int e = (i * 256 + tid) * 8;
      int row = e >> 5, col = e & 31;
      glds16(&A[(size_t)(m0 + row) * K + kbase + kt * 32 + col],
             &As[(i * 256 + (tid & ~63)) * 8]);
    }
#pragma unroll
    for (int i = 0; i < LB; ++i) {
      int e = (i * 256 + tid) * 8;
      int row = e >> 5, col = e & 31;
      glds16(&Bt[(size_t)(n0 + row) * K + kbase + kt * 32 + col],
             &Bs[(i * 256 + (tid & ~63)) * 8]);
    }
    __syncthreads();
    s16x8 af[AT], bf[BT];
#pragma unroll
    for (int mt = 0; mt < AT; ++mt)
      af[mt] = *(const s16x8*)&As[(wm * (BM / 2) + mt * 16 + l15) * 32 + quad * 8];
#pragma unroll
    for (int nt = 0; nt < BT; ++nt)
      bf[nt] = *(const s16x8*)&Bs[(wn * (BN / 2) + nt * 16 + l15) * 32 + quad * 8];
#pragma unroll
    for (int mt = 0; mt < AT; ++mt)
#pragma unroll
      for (int nt = 0; nt < BT; ++nt)
        acc[mt][nt] = __builtin_amdgcn_mfma_f32_16x16x32_bf16(af[mt], bf[nt], acc[mt][nt], 0, 0, 0);
  }

#pragma unroll
  for (int mt = 0; mt < AT; ++mt)
#pragma unroll
    for (int nt = 0; nt < BT; ++nt)
#pragma unroll
      for (int r = 0; r < 4; ++r) {
        int m = m0 + wm * (BM / 2) + mt * 16 + quad * 4 + r;
        int n = n0 + wn * (BN / 2) + nt * 16 + l15;
        unsafeAtomicAdd(&outF[(size_t)m * N + n], acc[mt][nt][r]);
      }
}

// ---------------- fused causal flash attention ------------------------------
__global__ __launch_bounds__(256) void attn_fused(
    const unsigned short* __restrict__ Q, const unsigned short* __restrict__ Kg,
    const unsigned short* __restrict__ Vt, unsigned short* __restrict__ Y) {
  __shared__ __align__(16) unsigned short Ks[64 * 72];
  __shared__ __align__(16) unsigned short Vs[64 * 72];
  __shared__ __align__(16) unsigned short Ps[4][16 * 72];
  int tid = threadIdx.x;
  int wv = tid >> 6, lane = tid & 63, quad = lane >> 4, l15 = lane & 15;
  int l = blockIdx.x;
  int w = l >> 8, s = l & 255;
  int g = s >> 5, i = s & 31;
  int qt, bh;
  if (w == 0)      { qt = i;              bh = g; }
  else if (w == 1) { qt = 31 - i;         bh = 8 + g; }
  else             { qt = (i + 16) & 31;  bh = 16 + g; }
  int bbx = bh / H_, hh = bh - bbx * H_;
  int q0 = qt * 64;
  size_t base = (size_t)bh * T_ * D_;
  size_t vbase = (size_t)bh * D_ * T_;
  int qrow = q0 + wv * 16 + l15;
  s16x8 qf0 = *(const s16x8*)&Q[base + (size_t)qrow * D_ + quad * 8];
  s16x8 qf1 = *(const s16x8*)&Q[base + (size_t)qrow * D_ + 32 + quad * 8];
  float lsum[4];
  fx4 oacc[4];
#pragma unroll
  for (int t = 0; t < 4; ++t) {
    lsum[t] = 0.f;
    oacc[t] = fx4{0.f, 0.f, 0.f, 0.f};
  }
  int r0s = tid >> 3;
  int c8 = (tid & 7) * 8;
  uint4 ka, kc, va, vc;
  {
    ka = *(const uint4*)&Kg[base + (size_t)r0s * D_ + c8];
    kc = *(const uint4*)&Kg[base + (size_t)(r0s + 32) * D_ + c8];
    va = *(const uint4*)&Vt[vbase + (size_t)r0s * T_ + c8];
    vc = *(const uint4*)&Vt[vbase + (size_t)(r0s + 32) * T_ + c8];
  }
  for (int kb = 0; kb <= qt; ++kb) {
    int k0 = kb * 64;
    __syncthreads();
    *(uint4*)&Ks[r0s * 72 + c8] = ka;
    *(uint4*)&Ks[(r0s + 32) * 72 + c8] = kc;
    *(uint4*)&Vs[r0s * 72 + c8] = va;
    *(uint4*)&Vs[(r0s + 32) * 72 + c8] = vc;
    __syncthreads();
    if (kb < qt) {
      int kn = k0 + 64;
      ka = *(const uint4*)&Kg[base + (size_t)(kn + r0s) * D_ + c8];
      kc = *(const uint4*)&Kg[base + (size_t)(kn + r0s + 32) * D_ + c8];
      va = *(const uint4*)&Vt[vbase + (size_t)r0s * T_ + kn + c8];
      vc = *(const uint4*)&Vt[vbase + (size_t)(r0s + 32) * T_ + kn + c8];
    }
    fx4 sc[4];
#pragma unroll
    for (int nt = 0; nt < 4; ++nt) {
      sc[nt] = fx4{0.f, 0.f, 0.f, 0.f};
      s16x8 kf0 = *(const s16x8*)&Ks[(nt * 16 + l15) * 72 + quad * 8];
      s16x8 kf1 = *(const s16x8*)&Ks[(nt * 16 + l15) * 72 + 32 + quad * 8];
      sc[nt] = __builtin_amdgcn_mfma_f32_16x16x32_bf16(qf0, kf0, sc[nt], 0, 0, 0);
      sc[nt] = __builtin_amdgcn_mfma_f32_16x16x32_bf16(qf1, kf1, sc[nt], 0, 0, 0);
    }
    bool diag = (kb == qt);
    unsigned short* pw = &Ps[wv][0];
#pragma unroll
    for (int nt = 0; nt < 4; ++nt)
#pragma unroll
      for (int r = 0; r < 4; ++r) {
        float p;
        if (diag && (k0 + nt * 16 + l15) > (q0 + wv * 16 + quad * 4 + r)) {
          p = 0.f;
        } else {
          p = __expf(sc[nt][r] * 0.125f);
        }
        lsum[r] += p;
        pw[(quad * 4 + r) * 72 + nt * 16 + l15] = f2bf(p);
      }
    s16x8 pa0 = *(const s16x8*)&pw[l15 * 72 + quad * 8];
    s16x8 pa1 = *(const s16x8*)&pw[l15 * 72 + 32 + quad * 8];
#pragma unroll
    for (int nt = 0; nt < 4; ++nt) {
      s16x8 vf0 = *(const s16x8*)&Vs[(nt * 16 + l15) * 72 + quad * 8];
      s16x8 vf1 = *(const s16x8*)&Vs[(nt * 16 + l15) * 72 + 32 + quad * 8];
      oacc[nt] = __builtin_amdgcn_mfma_f32_16x16x32_bf16(pa0, vf0, oacc[nt], 0, 0, 0);
      oacc[nt] = __builtin_amdgcn_mfma_f32_16x16x32_bf16(pa1, vf1, oacc[nt], 0, 0, 0);
    }
  }
#pragma unroll
  for (int r = 0; r < 4; ++r) {
#pragma unroll
    for (int off = 1; off < 16; off <<= 1) lsum[r] += __shfl_xor(lsum[r], off);
  }
#pragma unroll
  for (int nt = 0; nt < 4; ++nt)
#pragma unroll
    for (int r = 0; r < 4; ++r) {
      float o = oacc[nt][r] / lsum[r];
      int token = bbx * T_ + q0 + wv * 16 + quad * 4 + r;
      Y[(size_t)token * C_ + hh * D_ + nt * 16 + l15] = f2bf(o);
    }
}

// ---------------- launcher --------------------------------------------------
extern "C" void kernel_launch(void* const* d_in, const int* in_sizes, int n_in,
                              void* d_out, int out_size, void* d_ws, size_t ws_size,
                              hipStream_t stream) {
  const float* x      = (const float*)d_in[0];
  const float* ln1g   = (const float*)d_in[1];
  const float* ln1b   = (const float*)d_in[2];
  const float* Wattn  = (const float*)d_in[3];
  const float* battn  = (const float*)d_in[4];
  const float* Wcproj = (const float*)d_in[5];
  const float* bcproj = (const float*)d_in[6];
  const float* ln2g   = (const float*)d_in[7];
  const float* ln2b   = (const float*)d_in[8];
  const float* Wfc    = (const float*)d_in[9];
  const float* bfc    = (const float*)d_in[10];
  const float* Wmproj = (const float*)d_in[11];
  const float* bmproj = (const float*)d_in[12];
  float* out = (float*)d_out;
  char* ws = (char*)d_ws;

  unsigned short* WattnT  = (unsigned short*)(ws + 0);          // 2304x768 bf16
  unsigned short* WcprojT = (unsigned short*)(ws + 3538944);    // 768x768
  unsigned short* WfcT    = (unsigned short*)(ws + 4718592);    // 3072x768
  unsigned short* WmprojT = (unsigned short*)(ws + 9437184);    // 768x3072
  unsigned short* hbuf    = (unsigned short*)(ws + 14155776);   // 4096x768 bf16
  unsigned short* Qb      = (unsigned short*)(ws + 20447232);   // [24,2048,64]
  unsigned short* Kb      = (unsigned short*)(ws + 26738688);   // [24,2048,64]
  unsigned short* Vtb     = (unsigned short*)(ws + 33030144);   // [24,64,2048]
  unsigned short* Yb      = (unsigned short*)(ws + 39321600);   // 4096x768 bf16
  float*          x1      = (float*)(ws + 45613056);            // 4096x768 fp32
  unsigned short* Ab      = (unsigned short*)(ws + 58195968);   // 4096x3072 bf16

  transpose_cast<<<dim3(2304 / 32, 768 / 32), 256, 0, stream>>>(Wattn, WattnT, 768, 2304);
  transpose_cast<<<dim3(768 / 32, 768 / 32), 256, 0, stream>>>(Wcproj, WcprojT, 768, 768);
  transpose_cast<<<dim3(3072 / 32, 768 / 32), 256, 0, stream>>>(Wfc, WfcT, 768, 3072);
  transpose_cast<<<dim3(768 / 32, 3072 / 32), 256, 0, stream>>>(Wmproj, WmprojT, 3072, 768);

  layernorm_bf16<<<4096, 256, 0, stream>>>(x, ln1g, ln1b, hbuf);

  gemm_lds<128, 128, 0><<<dim3(2304 / 128, 4096 / 128), 256, 0, stream>>>(
      hbuf, WattnT, battn, nullptr, Qb, Kb, Vtb, 4096, 2304, 768);

  attn_fused<<<768, 256, 0, stream>>>(Qb, Kb, Vtb, Yb);

  // cproj: x1 = x + bias, then split-K=2 atomic GEMM
  add_bias_init<<<3072, 256, 0, stream>>>(x, bcproj, x1, 192);
  gemm_splitk<128, 64><<<dim3(768 / 64, 4096 / 128, 2), 256, 0, stream>>>(
      Yb, WcprojT, x1, 4096, 768, 768, 384);

  layernorm_bf16<<<4096, 256, 0, stream>>>(x1, ln2g, ln2b, hbuf);

  gemm_lds<128, 128, 2><<<dim3(3072 / 128, 4096 / 128), 256, 0, stream>>>(
      hbuf, WfcT, bfc, Ab, nullptr, nullptr, nullptr, 4096, 3072, 768);

  // mproj: out = x1 + bias, then split-K=4 atomic GEMM
  add_bias_init<<<3072, 256, 0, stream>>>(x1, bmproj, out, 192);
  gemm_splitk<128, 128><<<dim3(768 / 128, 4096 / 128, 4), 256, 0, stream>>>(
      Ab, WmprojT, out, 4096, 768, 3072, 768);
}

// Round 4
// 303.238 us; speedup vs baseline: 1.1272x; 1.1272x over previous
//
#include <hip/hip_runtime.h>
#include <cstdint>
#include <cstddef>

#define B_ 2
#define T_ 2048
#define C_ 768
#define H_ 12
#define D_ 64

typedef __attribute__((ext_vector_type(8))) short s16x8;
typedef __attribute__((ext_vector_type(4))) float fx4;

static __device__ __forceinline__ unsigned short f2bf(float f) {
  unsigned u = __builtin_bit_cast(unsigned, f);
  unsigned r = u + 0x7fffu + ((u >> 16) & 1u);
  return (unsigned short)(r >> 16);
}

static __device__ __forceinline__ void glds16(const unsigned short* g, unsigned short* l) {
  __builtin_amdgcn_global_load_lds(
      (const __attribute__((address_space(1))) void*)(g),
      (__attribute__((address_space(3))) void*)(l), 16, 0, 0);
}

// ---------------- weight transpose + cast: W[R][C] fp32 -> Wt[C][R] bf16 ----
__global__ __launch_bounds__(256) void transpose_cast(
    const float* __restrict__ W, unsigned short* __restrict__ Wt, int R, int C) {
  __shared__ float tile[32][33];
  int tx = threadIdx.x & 31;
  int ty = threadIdx.x >> 5;  // 0..7
  int c0 = blockIdx.x * 32, r0 = blockIdx.y * 32;
#pragma unroll
  for (int i = 0; i < 4; ++i)
    tile[ty + i * 8][tx] = W[(size_t)(r0 + ty + i * 8) * C + (c0 + tx)];
  __syncthreads();
#pragma unroll
  for (int i = 0; i < 4; ++i)
    Wt[(size_t)(c0 + ty + i * 8) * R + (r0 + tx)] = f2bf(tile[tx][ty + i * 8]);
}

// ---------------- layernorm fp32 -> bf16 ------------------------------------
__global__ __launch_bounds__(256) void layernorm_bf16(
    const float* __restrict__ X, const float* __restrict__ g,
    const float* __restrict__ bb, unsigned short* __restrict__ O) {
  int row = blockIdx.x, tid = threadIdx.x;
  const float* xr = X + (size_t)row * C_;
  float v0 = xr[tid], v1 = xr[tid + 256], v2 = xr[tid + 512];
  float s = v0 + v1 + v2;
  float s2 = v0 * v0 + v1 * v1 + v2 * v2;
#pragma unroll
  for (int off = 1; off < 64; off <<= 1) {
    s += __shfl_xor(s, off);
    s2 += __shfl_xor(s2, off);
  }
  __shared__ float ps[8];
  int wv = tid >> 6;
  if ((tid & 63) == 0) { ps[wv] = s; ps[wv + 4] = s2; }
  __syncthreads();
  s = ps[0] + ps[1] + ps[2] + ps[3];
  s2 = ps[4] + ps[5] + ps[6] + ps[7];
  float mu = s * (1.f / C_);
  float var = s2 * (1.f / C_) - mu * mu;
  float rstd = rsqrtf(var + 1e-5f);
  unsigned short* orow = O + (size_t)row * C_;
  orow[tid]       = f2bf((v0 - mu) * rstd * g[tid]       + bb[tid]);
  orow[tid + 256] = f2bf((v1 - mu) * rstd * g[tid + 256] + bb[tid + 256]);
  orow[tid + 512] = f2bf((v2 - mu) * rstd * g[tid + 512] + bb[tid + 512]);
}

// ---------------- double-buffered GEMM: C = A[M,K] * Bt[N,K]^T + bias -------
// 256 threads = 4 waves (2x2); glds width-16 staging; LDS double buffer so
// the k+1 stage is in flight during the k compute phase (crucial at the
// 1.5 block/CU occupancy of the N=768 GEMMs where no cross-block TLP exists).
// MODE 0: scatter into Q [bh,t,d], K [bh,t,d], Vt [bh,d,t]  (QKV)
// MODE 1: outF = resid + C + bias (fp32)   [grid: x = m-tile for L2 locality]
// MODE 2: outB = gelu(C + bias) (bf16)
template <int BM, int BN, int BK, int MODE>
__global__ __launch_bounds__(256) void gemm_db(
    const unsigned short* __restrict__ A, const unsigned short* __restrict__ Bt,
    const float* __restrict__ bias, const float* __restrict__ resid,
    float* __restrict__ outF, unsigned short* __restrict__ outB,
    unsigned short* __restrict__ qO, unsigned short* __restrict__ kO,
    unsigned short* __restrict__ vtO, int M, int N, int K) {
  constexpr int AT = BM / 32;
  constexpr int BT = BN / 32;
  constexpr int KS = BK / 32;
  constexpr int CA = BM * BK / 2048;   // 16B chunks per thread for A stage
  constexpr int CB = BN * BK / 2048;
  constexpr int ASZ = BM * BK, BSZ = BN * BK;
  __shared__ __align__(16) unsigned short As[2 * ASZ];
  __shared__ __align__(16) unsigned short Bs[2 * BSZ];
  int tid = threadIdx.x;
  int wv = tid >> 6, lane = tid & 63, quad = lane >> 4, l15 = lane & 15;
  int wm = wv >> 1, wn = wv & 1;
  int m0, n0;
  if (MODE == 1) { m0 = blockIdx.x * BM; n0 = blockIdx.y * BN; }
  else           { n0 = blockIdx.x * BN; m0 = blockIdx.y * BM; }
  fx4 acc[AT][BT];
#pragma unroll
  for (int i = 0; i < AT; ++i)
#pragma unroll
    for (int j = 0; j < BT; ++j) acc[i][j] = fx4{0.f, 0.f, 0.f, 0.f};

  int nk = K / BK;
  // prologue: stage tile 0 into buffer 0
#pragma unroll
  for (int i = 0; i < CA; ++i) {
    int e = (i * 256 + tid) * 8;
    glds16(&A[(size_t)(m0 + (e / BK)) * K + (e & (BK - 1))],
           &As[(i * 256 + (tid & ~63)) * 8]);
  }
#pragma unroll
  for (int i = 0; i < CB; ++i) {
    int e = (i * 256 + tid) * 8;
    glds16(&Bt[(size_t)(n0 + (e / BK)) * K + (e & (BK - 1))],
           &Bs[(i * 256 + (tid & ~63)) * 8]);
  }
  for (int kt = 0; kt < nk; ++kt) {
    int cur = kt & 1;
    __syncthreads();  // drains the glds for buf[cur]; prior reads of buf[cur^1] done
    if (kt + 1 < nk) {
      int kb = (kt + 1) * BK;
      int nxt = cur ^ 1;
#pragma unroll
      for (int i = 0; i < CA; ++i) {
        int e = (i * 256 + tid) * 8;
        glds16(&A[(size_t)(m0 + (e / BK)) * K + kb + (e & (BK - 1))],
               &As[nxt * ASZ + (i * 256 + (tid & ~63)) * 8]);
      }
#pragma unroll
      for (int i = 0; i < CB; ++i) {
        int e = (i * 256 + tid) * 8;
        glds16(&Bt[(size_t)(n0 + (e / BK)) * K + kb + (e & (BK - 1))],
               &Bs[nxt * BSZ + (i * 256 + (tid & ~63)) * 8]);
      }
    }
#pragma unroll
    for (int ks = 0; ks < KS; ++ks) {
      s16x8 af[AT], bf[BT];
#pragma unroll
      for (int mt = 0; mt < AT; ++mt)
        af[mt] = *(const s16x8*)&As[cur * ASZ + (wm * (BM / 2) + mt * 16 + l15) * BK + ks * 32 + quad * 8];
#pragma unroll
      for (int nt = 0; nt < BT; ++nt)
        bf[nt] = *(const s16x8*)&Bs[cur * BSZ + (wn * (BN / 2) + nt * 16 + l15) * BK + ks * 32 + quad * 8];
#pragma unroll
      for (int mt = 0; mt < AT; ++mt)
#pragma unroll
        for (int nt = 0; nt < BT; ++nt)
          acc[mt][nt] = __builtin_amdgcn_mfma_f32_16x16x32_bf16(af[mt], bf[nt], acc[mt][nt], 0, 0, 0);
    }
  }

#pragma unroll
  for (int mt = 0; mt < AT; ++mt)
#pragma unroll
    for (int nt = 0; nt < BT; ++nt)
#pragma unroll
      for (int r = 0; r < 4; ++r) {
        int m = m0 + wm * (BM / 2) + mt * 16 + quad * 4 + r;
        int n = n0 + wn * (BN / 2) + nt * 16 + l15;
        float v = acc[mt][nt][r] + bias[n];
        if (MODE == 0) {
          int which = n / C_;
          int within = n - which * C_;
          int hd = within >> 6, d = within & 63;
          int bbx = m >> 11, t = m & 2047;
          size_t bh = (size_t)(bbx * H_ + hd);
          unsigned short bv = f2bf(v);
          if (which == 0)      qO[(bh * T_ + t) * D_ + d] = bv;
          else if (which == 1) kO[(bh * T_ + t) * D_ + d] = bv;
          else                 vtO[(bh * D_ + d) * T_ + t] = bv;
        } else if (MODE == 1) {
          outF[(size_t)m * N + n] = resid[(size_t)m * N + n] + v;
        } else {
          float gl = 0.5f * v * (1.f + erff(v * 0.70710678118654752f));
          outB[(size_t)m * N + n] = f2bf(gl);
        }
      }
}

// ---------------- fused causal flash attention ------------------------------
__global__ __launch_bounds__(256) void attn_fused(
    const unsigned short* __restrict__ Q, const unsigned short* __restrict__ Kg,
    const unsigned short* __restrict__ Vt, unsigned short* __restrict__ Y) {
  __shared__ __align__(16) unsigned short Ks[64 * 72];
  __shared__ __align__(16) unsigned short Vs[64 * 72];
  __shared__ __align__(16) unsigned short Ps[4][16 * 72];
  int tid = threadIdx.x;
  int wv = tid >> 6, lane = tid & 63, quad = lane >> 4, l15 = lane & 15;
  int l = blockIdx.x;
  int w = l >> 8, s = l & 255;
  int g = s >> 5, i = s & 31;
  int qt, bh;
  if (w == 0)      { qt = i;              bh = g; }
  else if (w == 1) { qt = 31 - i;         bh = 8 + g; }
  else             { qt = (i + 16) & 31;  bh = 16 + g; }
  int bbx = bh / H_, hh = bh - bbx * H_;
  int q0 = qt * 64;
  size_t base = (size_t)bh * T_ * D_;
  size_t vbase = (size_t)bh * D_ * T_;
  int qrow = q0 + wv * 16 + l15;
  s16x8 qf0 = *(const s16x8*)&Q[base + (size_t)qrow * D_ + quad * 8];
  s16x8 qf1 = *(const s16x8*)&Q[base + (size_t)qrow * D_ + 32 + quad * 8];
  float lsum[4];
  fx4 oacc[4];
#pragma unroll
  for (int t = 0; t < 4; ++t) {
    lsum[t] = 0.f;
    oacc[t] = fx4{0.f, 0.f, 0.f, 0.f};
  }
  int r0s = tid >> 3;
  int c8 = (tid & 7) * 8;
  uint4 ka, kc, va, vc;
  {
    ka = *(const uint4*)&Kg[base + (size_t)r0s * D_ + c8];
    kc = *(const uint4*)&Kg[base + (size_t)(r0s + 32) * D_ + c8];
    va = *(const uint4*)&Vt[vbase + (size_t)r0s * T_ + c8];
    vc = *(const uint4*)&Vt[vbase + (size_t)(r0s + 32) * T_ + c8];
  }
  for (int kb = 0; kb <= qt; ++kb) {
    int k0 = kb * 64;
    __syncthreads();
    *(uint4*)&Ks[r0s * 72 + c8] = ka;
    *(uint4*)&Ks[(r0s + 32) * 72 + c8] = kc;
    *(uint4*)&Vs[r0s * 72 + c8] = va;
    *(uint4*)&Vs[(r0s + 32) * 72 + c8] = vc;
    __syncthreads();
    if (kb < qt) {
      int kn = k0 + 64;
      ka = *(const uint4*)&Kg[base + (size_t)(kn + r0s) * D_ + c8];
      kc = *(const uint4*)&Kg[base + (size_t)(kn + r0s + 32) * D_ + c8];
      va = *(const uint4*)&Vt[vbase + (size_t)r0s * T_ + kn + c8];
      vc = *(const uint4*)&Vt[vbase + (size_t)(r0s + 32) * T_ + kn + c8];
    }
    fx4 sc[4];
#pragma unroll
    for (int nt = 0; nt < 4; ++nt) {
      sc[nt] = fx4{0.f, 0.f, 0.f, 0.f};
      s16x8 kf0 = *(const s16x8*)&Ks[(nt * 16 + l15) * 72 + quad * 8];
      s16x8 kf1 = *(const s16x8*)&Ks[(nt * 16 + l15) * 72 + 32 + quad * 8];
      sc[nt] = __builtin_amdgcn_mfma_f32_16x16x32_bf16(qf0, kf0, sc[nt], 0, 0, 0);
      sc[nt] = __builtin_amdgcn_mfma_f32_16x16x32_bf16(qf1, kf1, sc[nt], 0, 0, 0);
    }
    bool diag = (kb == qt);
    unsigned short* pw = &Ps[wv][0];
#pragma unroll
    for (int nt = 0; nt < 4; ++nt)
#pragma unroll
      for (int r = 0; r < 4; ++r) {
        float p;
        if (diag && (k0 + nt * 16 + l15) > (q0 + wv * 16 + quad * 4 + r)) {
          p = 0.f;
        } else {
          p = __expf(sc[nt][r] * 0.125f);
        }
        lsum[r] += p;
        pw[(quad * 4 + r) * 72 + nt * 16 + l15] = f2bf(p);
      }
    s16x8 pa0 = *(const s16x8*)&pw[l15 * 72 + quad * 8];
    s16x8 pa1 = *(const s16x8*)&pw[l15 * 72 + 32 + quad * 8];
#pragma unroll
    for (int nt = 0; nt < 4; ++nt) {
      s16x8 vf0 = *(const s16x8*)&Vs[(nt * 16 + l15) * 72 + quad * 8];
      s16x8 vf1 = *(const s16x8*)&Vs[(nt * 16 + l15) * 72 + 32 + quad * 8];
      oacc[nt] = __builtin_amdgcn_mfma_f32_16x16x32_bf16(pa0, vf0, oacc[nt], 0, 0, 0);
      oacc[nt] = __builtin_amdgcn_mfma_f32_16x16x32_bf16(pa1, vf1, oacc[nt], 0, 0, 0);
    }
  }
#pragma unroll
  for (int r = 0; r < 4; ++r) {
#pragma unroll
    for (int off = 1; off < 16; off <<= 1) lsum[r] += __shfl_xor(lsum[r], off);
  }
#pragma unroll
  for (int nt = 0; nt < 4; ++nt)
#pragma unroll
    for (int r = 0; r < 4; ++r) {
      float o = oacc[nt][r] / lsum[r];
      int token = bbx * T_ + q0 + wv * 16 + quad * 4 + r;
      Y[(size_t)token * C_ + hh * D_ + nt * 16 + l15] = f2bf(o);
    }
}

// ---------------- launcher --------------------------------------------------
extern "C" void kernel_launch(void* const* d_in, const int* in_sizes, int n_in,
                              void* d_out, int out_size, void* d_ws, size_t ws_size,
                              hipStream_t stream) {
  const float* x      = (const float*)d_in[0];
  const float* ln1g   = (const float*)d_in[1];
  const float* ln1b   = (const float*)d_in[2];
  const float* Wattn  = (const float*)d_in[3];
  const float* battn  = (const float*)d_in[4];
  const float* Wcproj = (const float*)d_in[5];
  const float* bcproj = (const float*)d_in[6];
  const float* ln2g   = (const float*)d_in[7];
  const float* ln2b   = (const float*)d_in[8];
  const float* Wfc    = (const float*)d_in[9];
  const float* bfc    = (const float*)d_in[10];
  const float* Wmproj = (const float*)d_in[11];
  const float* bmproj = (const float*)d_in[12];
  float* out = (float*)d_out;
  char* ws = (char*)d_ws;

  unsigned short* WattnT  = (unsigned short*)(ws + 0);          // 2304x768 bf16
  unsigned short* WcprojT = (unsigned short*)(ws + 3538944);    // 768x768
  unsigned short* WfcT    = (unsigned short*)(ws + 4718592);    // 3072x768
  unsigned short* WmprojT = (unsigned short*)(ws + 9437184);    // 768x3072
  unsigned short* hbuf    = (unsigned short*)(ws + 14155776);   // 4096x768 bf16
  unsigned short* Qb      = (unsigned short*)(ws + 20447232);   // [24,2048,64]
  unsigned short* Kb      = (unsigned short*)(ws + 26738688);   // [24,2048,64]
  unsigned short* Vtb     = (unsigned short*)(ws + 33030144);   // [24,64,2048]
  unsigned short* Yb      = (unsigned short*)(ws + 39321600);   // 4096x768 bf16
  float*          x1      = (float*)(ws + 45613056);            // 4096x768 fp32
  unsigned short* Ab      = (unsigned short*)(ws + 58195968);   // 4096x3072 bf16

  transpose_cast<<<dim3(2304 / 32, 768 / 32), 256, 0, stream>>>(Wattn, WattnT, 768, 2304);
  transpose_cast<<<dim3(768 / 32, 768 / 32), 256, 0, stream>>>(Wcproj, WcprojT, 768, 768);
  transpose_cast<<<dim3(3072 / 32, 768 / 32), 256, 0, stream>>>(Wfc, WfcT, 768, 3072);
  transpose_cast<<<dim3(768 / 32, 3072 / 32), 256, 0, stream>>>(Wmproj, WmprojT, 3072, 768);

  layernorm_bf16<<<4096, 256, 0, stream>>>(x, ln1g, ln1b, hbuf);

  gemm_db<128, 128, 32, 0><<<dim3(2304 / 128, 4096 / 128), 256, 0, stream>>>(
      hbuf, WattnT, battn, nullptr, nullptr, nullptr, Qb, Kb, Vtb, 4096, 2304, 768);

  attn_fused<<<768, 256, 0, stream>>>(Qb, Kb, Vtb, Yb);

  // cproj: x1 = x + Yb*Wc + bias  (m-tile fastest in grid.x for L2 locality)
  gemm_db<128, 64, 64, 1><<<dim3(4096 / 128, 768 / 64), 256, 0, stream>>>(
      Yb, WcprojT, bcproj, x, x1, nullptr, nullptr, nullptr, nullptr, 4096, 768, 768);

  layernorm_bf16<<<4096, 256, 0, stream>>>(x1, ln2g, ln2b, hbuf);

  gemm_db<128, 128, 32, 2><<<dim3(3072 / 128, 4096 / 128), 256, 0, stream>>>(
      hbuf, WfcT, bfc, nullptr, nullptr, Ab, nullptr, nullptr, nullptr, 4096, 3072, 768);

  // mproj: out = x1 + Ab*Wm + bias
  gemm_db<128, 64, 64, 1><<<dim3(4096 / 128, 768 / 64), 256, 0, stream>>>(
      Ab, WmprojT, bmproj, x1, out, nullptr, nullptr, nullptr, nullptr, 4096, 768, 3072);
}

// Round 5
// 291.094 us; speedup vs baseline: 1.1742x; 1.0417x over previous
//
#include <hip/hip_runtime.h>
#include <cstdint>
#include <cstddef>

#define B_ 2
#define T_ 2048
#define C_ 768
#define H_ 12
#define D_ 64

typedef __attribute__((ext_vector_type(8))) short s16x8;
typedef __attribute__((ext_vector_type(4))) float fx4;

static __device__ __forceinline__ unsigned short f2bf(float f) {
  unsigned u = __builtin_bit_cast(unsigned, f);
  unsigned r = u + 0x7fffu + ((u >> 16) & 1u);
  return (unsigned short)(r >> 16);
}

static __device__ __forceinline__ void glds16(const unsigned short* g, unsigned short* l) {
  __builtin_amdgcn_global_load_lds(
      (const __attribute__((address_space(1))) void*)(g),
      (__attribute__((address_space(3))) void*)(l), 16, 0, 0);
}

// ---------------- weight transpose + cast: W[R][C] fp32 -> Wt[C][R] bf16 ----
__global__ __launch_bounds__(256) void transpose_cast(
    const float* __restrict__ W, unsigned short* __restrict__ Wt, int R, int C) {
  __shared__ float tile[32][33];
  int tx = threadIdx.x & 31;
  int ty = threadIdx.x >> 5;  // 0..7
  int c0 = blockIdx.x * 32, r0 = blockIdx.y * 32;
#pragma unroll
  for (int i = 0; i < 4; ++i)
    tile[ty + i * 8][tx] = W[(size_t)(r0 + ty + i * 8) * C + (c0 + tx)];
  __syncthreads();
#pragma unroll
  for (int i = 0; i < 4; ++i)
    Wt[(size_t)(c0 + ty + i * 8) * R + (r0 + tx)] = f2bf(tile[tx][ty + i * 8]);
}

// ---------------- layernorm fp32 -> bf16 ------------------------------------
__global__ __launch_bounds__(256) void layernorm_bf16(
    const float* __restrict__ X, const float* __restrict__ g,
    const float* __restrict__ bb, unsigned short* __restrict__ O) {
  int row = blockIdx.x, tid = threadIdx.x;
  const float* xr = X + (size_t)row * C_;
  float v0 = xr[tid], v1 = xr[tid + 256], v2 = xr[tid + 512];
  float s = v0 + v1 + v2;
  float s2 = v0 * v0 + v1 * v1 + v2 * v2;
#pragma unroll
  for (int off = 1; off < 64; off <<= 1) {
    s += __shfl_xor(s, off);
    s2 += __shfl_xor(s2, off);
  }
  __shared__ float ps[8];
  int wv = tid >> 6;
  if ((tid & 63) == 0) { ps[wv] = s; ps[wv + 4] = s2; }
  __syncthreads();
  s = ps[0] + ps[1] + ps[2] + ps[3];
  s2 = ps[4] + ps[5] + ps[6] + ps[7];
  float mu = s * (1.f / C_);
  float var = s2 * (1.f / C_) - mu * mu;
  float rstd = rsqrtf(var + 1e-5f);
  unsigned short* orow = O + (size_t)row * C_;
  orow[tid]       = f2bf((v0 - mu) * rstd * g[tid]       + bb[tid]);
  orow[tid + 256] = f2bf((v1 - mu) * rstd * g[tid + 256] + bb[tid + 256]);
  orow[tid + 512] = f2bf((v2 - mu) * rstd * g[tid + 512] + bb[tid + 512]);
}

// ---------------- double-buffered GEMM: C = A[M,K] * Bt[N,K]^T + bias -------
// 256 threads = 4 waves (2x2); glds width-16 staging; LDS double buffer.
// BK==64 uses an XOR swizzle on the 8-element column group so the MFMA
// fragment ds_read_b128 (row stride 128 B = 32 banks) doesn't put all 16
// lanes on one 4-bank group (16-way conflict, r4's 1.06e7 counter).
// Swizzle: LDS slot (row, c8) holds global col-group c8 ^ (row & 7); the
// store side permutes the *global source* index (glds dest layout is fixed).
// MODE 0: scatter into Q [bh,t,d], K [bh,t,d], Vt [bh,d,t]  (QKV)
// MODE 1: outF = resid + C + bias (fp32)   [grid: x = m-tile for L2 locality]
// MODE 2: outB = gelu(C + bias) (bf16)
template <int BM, int BN, int BK, int MODE>
__global__ __launch_bounds__(256) void gemm_db(
    const unsigned short* __restrict__ A, const unsigned short* __restrict__ Bt,
    const float* __restrict__ bias, const float* __restrict__ resid,
    float* __restrict__ outF, unsigned short* __restrict__ outB,
    unsigned short* __restrict__ qO, unsigned short* __restrict__ kO,
    unsigned short* __restrict__ vtO, int M, int N, int K) {
  constexpr int AT = BM / 32;
  constexpr int BT = BN / 32;
  constexpr int KS = BK / 32;
  constexpr int CA = BM * BK / 2048;   // 16B chunks per thread for A stage
  constexpr int CB = BN * BK / 2048;
  constexpr int ASZ = BM * BK, BSZ = BN * BK;
  constexpr bool SWIZ = (BK == 64);
  __shared__ __align__(16) unsigned short As[2 * ASZ];
  __shared__ __align__(16) unsigned short Bs[2 * BSZ];
  int tid = threadIdx.x;
  int wv = tid >> 6, lane = tid & 63, quad = lane >> 4, l15 = lane & 15;
  int wm = wv >> 1, wn = wv & 1;
  int m0, n0;
  if (MODE == 1) { m0 = blockIdx.x * BM; n0 = blockIdx.y * BN; }
  else           { n0 = blockIdx.x * BN; m0 = blockIdx.y * BM; }
  fx4 acc[AT][BT];
#pragma unroll
  for (int i = 0; i < AT; ++i)
#pragma unroll
    for (int j = 0; j < BT; ++j) acc[i][j] = fx4{0.f, 0.f, 0.f, 0.f};

  int nk = K / BK;
  // prologue: stage tile 0 into buffer 0
#pragma unroll
  for (int i = 0; i < CA; ++i) {
    int e = (i * 256 + tid) * 8;
    int row = e / BK, col = e & (BK - 1);
    if (SWIZ) col = (((col >> 3) ^ (row & 7)) << 3);
    glds16(&A[(size_t)(m0 + row) * K + col], &As[(i * 256 + (tid & ~63)) * 8]);
  }
#pragma unroll
  for (int i = 0; i < CB; ++i) {
    int e = (i * 256 + tid) * 8;
    int row = e / BK, col = e & (BK - 1);
    if (SWIZ) col = (((col >> 3) ^ (row & 7)) << 3);
    glds16(&Bt[(size_t)(n0 + row) * K + col], &Bs[(i * 256 + (tid & ~63)) * 8]);
  }
  for (int kt = 0; kt < nk; ++kt) {
    int cur = kt & 1;
    __syncthreads();  // drains glds for buf[cur]; prefetch below waits at next barrier
    if (kt + 1 < nk) {
      int kb = (kt + 1) * BK;
      int nxt = cur ^ 1;
#pragma unroll
      for (int i = 0; i < CA; ++i) {
        int e = (i * 256 + tid) * 8;
        int row = e / BK, col = e & (BK - 1);
        if (SWIZ) col = (((col >> 3) ^ (row & 7)) << 3);
        glds16(&A[(size_t)(m0 + row) * K + kb + col],
               &As[nxt * ASZ + (i * 256 + (tid & ~63)) * 8]);
      }
#pragma unroll
      for (int i = 0; i < CB; ++i) {
        int e = (i * 256 + tid) * 8;
        int row = e / BK, col = e & (BK - 1);
        if (SWIZ) col = (((col >> 3) ^ (row & 7)) << 3);
        glds16(&Bt[(size_t)(n0 + row) * K + kb + col],
               &Bs[nxt * BSZ + (i * 256 + (tid & ~63)) * 8]);
      }
    }
#pragma unroll
    for (int ks = 0; ks < KS; ++ks) {
      s16x8 af[AT], bf[BT];
#pragma unroll
      for (int mt = 0; mt < AT; ++mt) {
        int r = wm * (BM / 2) + mt * 16 + l15;
        int c = ks * 32 + quad * 8;
        if (SWIZ) c = (((c >> 3) ^ (r & 7)) << 3);
        af[mt] = *(const s16x8*)&As[cur * ASZ + r * BK + c];
      }
#pragma unroll
      for (int nt = 0; nt < BT; ++nt) {
        int r = wn * (BN / 2) + nt * 16 + l15;
        int c = ks * 32 + quad * 8;
        if (SWIZ) c = (((c >> 3) ^ (r & 7)) << 3);
        bf[nt] = *(const s16x8*)&Bs[cur * BSZ + r * BK + c];
      }
#pragma unroll
      for (int mt = 0; mt < AT; ++mt)
#pragma unroll
        for (int nt = 0; nt < BT; ++nt)
          acc[mt][nt] = __builtin_amdgcn_mfma_f32_16x16x32_bf16(af[mt], bf[nt], acc[mt][nt], 0, 0, 0);
    }
  }

#pragma unroll
  for (int mt = 0; mt < AT; ++mt)
#pragma unroll
    for (int nt = 0; nt < BT; ++nt)
#pragma unroll
      for (int r = 0; r < 4; ++r) {
        int m = m0 + wm * (BM / 2) + mt * 16 + quad * 4 + r;
        int n = n0 + wn * (BN / 2) + nt * 16 + l15;
        float v = acc[mt][nt][r] + bias[n];
        if (MODE == 0) {
          int which = n / C_;
          int within = n - which * C_;
          int hd = within >> 6, d = within & 63;
          int bbx = m >> 11, t = m & 2047;
          size_t bh = (size_t)(bbx * H_ + hd);
          unsigned short bv = f2bf(v);
          if (which == 0)      qO[(bh * T_ + t) * D_ + d] = bv;
          else if (which == 1) kO[(bh * T_ + t) * D_ + d] = bv;
          else                 vtO[(bh * D_ + d) * T_ + t] = bv;
        } else if (MODE == 1) {
          outF[(size_t)m * N + n] = resid[(size_t)m * N + n] + v;
        } else {
          float gl = 0.5f * v * (1.f + erff(v * 0.70710678118654752f));
          outB[(size_t)m * N + n] = f2bf(gl);
        }
      }
}

// ---------------- fused causal flash attention ------------------------------
__global__ __launch_bounds__(256) void attn_fused(
    const unsigned short* __restrict__ Q, const unsigned short* __restrict__ Kg,
    const unsigned short* __restrict__ Vt, unsigned short* __restrict__ Y) {
  __shared__ __align__(16) unsigned short Ks[64 * 72];
  __shared__ __align__(16) unsigned short Vs[64 * 72];
  __shared__ __align__(16) unsigned short Ps[4][16 * 72];
  int tid = threadIdx.x;
  int wv = tid >> 6, lane = tid & 63, quad = lane >> 4, l15 = lane & 15;
  int l = blockIdx.x;
  int w = l >> 8, s = l & 255;
  int g = s >> 5, i = s & 31;
  int qt, bh;
  if (w == 0)      { qt = i;              bh = g; }
  else if (w == 1) { qt = 31 - i;         bh = 8 + g; }
  else             { qt = (i + 16) & 31;  bh = 16 + g; }
  int bbx = bh / H_, hh = bh - bbx * H_;
  int q0 = qt * 64;
  size_t base = (size_t)bh * T_ * D_;
  size_t vbase = (size_t)bh * D_ * T_;
  int qrow = q0 + wv * 16 + l15;
  s16x8 qf0 = *(const s16x8*)&Q[base + (size_t)qrow * D_ + quad * 8];
  s16x8 qf1 = *(const s16x8*)&Q[base + (size_t)qrow * D_ + 32 + quad * 8];
  float lsum[4];
  fx4 oacc[4];
#pragma unroll
  for (int t = 0; t < 4; ++t) {
    lsum[t] = 0.f;
    oacc[t] = fx4{0.f, 0.f, 0.f, 0.f};
  }
  int r0s = tid >> 3;
  int c8 = (tid & 7) * 8;
  uint4 ka, kc, va, vc;
  {
    ka = *(const uint4*)&Kg[base + (size_t)r0s * D_ + c8];
    kc = *(const uint4*)&Kg[base + (size_t)(r0s + 32) * D_ + c8];
    va = *(const uint4*)&Vt[vbase + (size_t)r0s * T_ + c8];
    vc = *(const uint4*)&Vt[vbase + (size_t)(r0s + 32) * T_ + c8];
  }
  for (int kb = 0; kb <= qt; ++kb) {
    int k0 = kb * 64;
    __syncthreads();
    *(uint4*)&Ks[r0s * 72 + c8] = ka;
    *(uint4*)&Ks[(r0s + 32) * 72 + c8] = kc;
    *(uint4*)&Vs[r0s * 72 + c8] = va;
    *(uint4*)&Vs[(r0s + 32) * 72 + c8] = vc;
    __syncthreads();
    if (kb < qt) {
      int kn = k0 + 64;
      ka = *(const uint4*)&Kg[base + (size_t)(kn + r0s) * D_ + c8];
      kc = *(const uint4*)&Kg[base + (size_t)(kn + r0s + 32) * D_ + c8];
      va = *(const uint4*)&Vt[vbase + (size_t)r0s * T_ + kn + c8];
      vc = *(const uint4*)&Vt[vbase + (size_t)(r0s + 32) * T_ + kn + c8];
    }
    fx4 sc[4];
#pragma unroll
    for (int nt = 0; nt < 4; ++nt) {
      sc[nt] = fx4{0.f, 0.f, 0.f, 0.f};
      s16x8 kf0 = *(const s16x8*)&Ks[(nt * 16 + l15) * 72 + quad * 8];
      s16x8 kf1 = *(const s16x8*)&Ks[(nt * 16 + l15) * 72 + 32 + quad * 8];
      sc[nt] = __builtin_amdgcn_mfma_f32_16x16x32_bf16(qf0, kf0, sc[nt], 0, 0, 0);
      sc[nt] = __builtin_amdgcn_mfma_f32_16x16x32_bf16(qf1, kf1, sc[nt], 0, 0, 0);
    }
    bool diag = (kb == qt);
    unsigned short* pw = &Ps[wv][0];
#pragma unroll
    for (int nt = 0; nt < 4; ++nt)
#pragma unroll
      for (int r = 0; r < 4; ++r) {
        float p;
        if (diag && (k0 + nt * 16 + l15) > (q0 + wv * 16 + quad * 4 + r)) {
          p = 0.f;
        } else {
          p = __expf(sc[nt][r] * 0.125f);
        }
        lsum[r] += p;
        pw[(quad * 4 + r) * 72 + nt * 16 + l15] = f2bf(p);
      }
    s16x8 pa0 = *(const s16x8*)&pw[l15 * 72 + quad * 8];
    s16x8 pa1 = *(const s16x8*)&pw[l15 * 72 + 32 + quad * 8];
#pragma unroll
    for (int nt = 0; nt < 4; ++nt) {
      s16x8 vf0 = *(const s16x8*)&Vs[(nt * 16 + l15) * 72 + quad * 8];
      s16x8 vf1 = *(const s16x8*)&Vs[(nt * 16 + l15) * 72 + 32 + quad * 8];
      oacc[nt] = __builtin_amdgcn_mfma_f32_16x16x32_bf16(pa0, vf0, oacc[nt], 0, 0, 0);
      oacc[nt] = __builtin_amdgcn_mfma_f32_16x16x32_bf16(pa1, vf1, oacc[nt], 0, 0, 0);
    }
  }
#pragma unroll
  for (int r = 0; r < 4; ++r) {
#pragma unroll
    for (int off = 1; off < 16; off <<= 1) lsum[r] += __shfl_xor(lsum[r], off);
  }
#pragma unroll
  for (int nt = 0; nt < 4; ++nt)
#pragma unroll
    for (int r = 0; r < 4; ++r) {
      float o = oacc[nt][r] / lsum[r];
      int token = bbx * T_ + q0 + wv * 16 + quad * 4 + r;
      Y[(size_t)token * C_ + hh * D_ + nt * 16 + l15] = f2bf(o);
    }
}

// ---------------- launcher --------------------------------------------------
extern "C" void kernel_launch(void* const* d_in, const int* in_sizes, int n_in,
                              void* d_out, int out_size, void* d_ws, size_t ws_size,
                              hipStream_t stream) {
  const float* x      = (const float*)d_in[0];
  const float* ln1g   = (const float*)d_in[1];
  const float* ln1b   = (const float*)d_in[2];
  const float* Wattn  = (const float*)d_in[3];
  const float* battn  = (const float*)d_in[4];
  const float* Wcproj = (const float*)d_in[5];
  const float* bcproj = (const float*)d_in[6];
  const float* ln2g   = (const float*)d_in[7];
  const float* ln2b   = (const float*)d_in[8];
  const float* Wfc    = (const float*)d_in[9];
  const float* bfc    = (const float*)d_in[10];
  const float* Wmproj = (const float*)d_in[11];
  const float* bmproj = (const float*)d_in[12];
  float* out = (float*)d_out;
  char* ws = (char*)d_ws;

  unsigned short* WattnT  = (unsigned short*)(ws + 0);          // 2304x768 bf16
  unsigned short* WcprojT = (unsigned short*)(ws + 3538944);    // 768x768
  unsigned short* WfcT    = (unsigned short*)(ws + 4718592);    // 3072x768
  unsigned short* WmprojT = (unsigned short*)(ws + 9437184);    // 768x3072
  unsigned short* hbuf    = (unsigned short*)(ws + 14155776);   // 4096x768 bf16
  unsigned short* Qb      = (unsigned short*)(ws + 20447232);   // [24,2048,64]
  unsigned short* Kb      = (unsigned short*)(ws + 26738688);   // [24,2048,64]
  unsigned short* Vtb     = (unsigned short*)(ws + 33030144);   // [24,64,2048]
  unsigned short* Yb      = (unsigned short*)(ws + 39321600);   // 4096x768 bf16
  float*          x1      = (float*)(ws + 45613056);            // 4096x768 fp32
  unsigned short* Ab      = (unsigned short*)(ws + 58195968);   // 4096x3072 bf16

  transpose_cast<<<dim3(2304 / 32, 768 / 32), 256, 0, stream>>>(Wattn, WattnT, 768, 2304);
  transpose_cast<<<dim3(768 / 32, 768 / 32), 256, 0, stream>>>(Wcproj, WcprojT, 768, 768);
  transpose_cast<<<dim3(3072 / 32, 768 / 32), 256, 0, stream>>>(Wfc, WfcT, 768, 3072);
  transpose_cast<<<dim3(768 / 32, 3072 / 32), 256, 0, stream>>>(Wmproj, WmprojT, 3072, 768);

  layernorm_bf16<<<4096, 256, 0, stream>>>(x, ln1g, ln1b, hbuf);

  gemm_db<128, 128, 32, 0><<<dim3(2304 / 128, 4096 / 128), 256, 0, stream>>>(
      hbuf, WattnT, battn, nullptr, nullptr, nullptr, Qb, Kb, Vtb, 4096, 2304, 768);

  attn_fused<<<768, 256, 0, stream>>>(Qb, Kb, Vtb, Yb);

  // cproj: x1 = x + Yb*Wc + bias  (m-tile fastest in grid.x for L2 locality)
  gemm_db<128, 64, 64, 1><<<dim3(4096 / 128, 768 / 64), 256, 0, stream>>>(
      Yb, WcprojT, bcproj, x, x1, nullptr, nullptr, nullptr, nullptr, 4096, 768, 768);

  layernorm_bf16<<<4096, 256, 0, stream>>>(x1, ln2g, ln2b, hbuf);

  gemm_db<128, 128, 32, 2><<<dim3(3072 / 128, 4096 / 128), 256, 0, stream>>>(
      hbuf, WfcT, bfc, nullptr, nullptr, Ab, nullptr, nullptr, nullptr, 4096, 3072, 768);

  // mproj: out = x1 + Ab*Wm + bias
  gemm_db<128, 64, 64, 1><<<dim3(4096 / 128, 768 / 64), 256, 0, stream>>>(
      Ab, WmprojT, bmproj, x1, out, nullptr, nullptr, nullptr, nullptr, 4096, 768, 3072);
}